// Round 12
// baseline (47938.431 us; speedup 1.0000x reference)
//
#include <hip/hip_runtime.h>
#include <hip/hip_bf16.h>
#include <cmath>

typedef __attribute__((ext_vector_type(8))) short bf16x8;
typedef __attribute__((ext_vector_type(4))) float f32x4;
typedef unsigned int u32;

#define DEVI __device__ __forceinline__

DEVI float sigf(float x) { return 1.0f / (1.0f + __expf(-x)); }

// async global->LDS, 16B per lane. LDS dest must be wave-uniform base (HW adds lane*16).
typedef const __attribute__((address_space(1))) u32* gas_t;
typedef __attribute__((address_space(3))) u32* las_t;
DEVI void g2l16(const void* g, void* l) {
  __builtin_amdgcn_global_load_lds((gas_t)g, (las_t)l, 16, 0, 0);
}

// ---- problem constants
#define BATCH 1024
#define CODE  2048
#define RNN   512
#define NG    2048      // 4*RNN
#define TSTEPS 128
#define K1K   2560      // CODE + RNN
#define K2K   1024
#define K3K   512

#define BUFSZ 16384     // one BK=64 tile: A[64][128B] + B[64][128B]
#define NBLK  512u      // persistent grid size (2 blocks/CU, provably co-resident)

// ---------------------------------------------------------------------------
// prologue kernels (run every launch; d_ws is re-poisoned before each launch)
// ---------------------------------------------------------------------------

__global__ void conv_w1(const float* __restrict__ w_ih1, const float* __restrict__ w_hh1,
                        __hip_bfloat16* __restrict__ W1T) {
  int np = blockIdx.x;                       // 0..2047, gate-interleaved: np = 4u+g
  int co = (np & 3) * RNN + (np >> 2);       // original gate column
  for (int k = threadIdx.x; k < K1K; k += 256) {
    float v = (k < CODE) ? w_ih1[(size_t)k * NG + co]
                         : w_hh1[(size_t)(k - CODE) * NG + co];
    W1T[(size_t)np * K1K + k] = __float2bfloat16(v);
  }
}

__global__ void conv_w2(const float* __restrict__ w_ih2, const float* __restrict__ w_hh2,
                        __hip_bfloat16* __restrict__ W2T) {
  int np = blockIdx.x;
  int co = (np & 3) * RNN + (np >> 2);
  for (int k = threadIdx.x; k < K2K; k += 256) {
    float v = (k < RNN) ? w_ih2[(size_t)k * NG + co]
                        : w_hh2[(size_t)(k - RNN) * NG + co];
    W2T[(size_t)np * K2K + k] = __float2bfloat16(v);
  }
}

// WoT[n][k], n<2048 (att only; heads handled separately)
__global__ void conv_wo(const float* __restrict__ w_att, __hip_bfloat16* __restrict__ WoT) {
  int n = blockIdx.x;  // 0..2047
  for (int k = threadIdx.x; k < K3K; k += 256)
    WoT[(size_t)n * K3K + k] = __float2bfloat16(w_att[(size_t)k * CODE + n]);
}

__global__ void conv_b(const float* b_ih1, const float* b_hh1,
                       const float* b_ih2, const float* b_hh2,
                       const float* b_att,
                       float* b1p, float* b2p, float* bo) {
  int i = blockIdx.x * 256 + threadIdx.x;
  if (i < NG) {
    int co = (i & 3) * RNN + (i >> 2);
    b1p[i] = b_ih1[co] + b_hh1[co];
    b2p[i] = b_ih2[co] + b_hh2[co];
    bo[i] = b_att[i];   // natural order, i < 2048 == NG
  }
}

// zero hbuf0(2MB)+c1(2MB)+c2(2MB) contiguous + the h1 strip of xbuf + barrier
__global__ void init_zero(char* __restrict__ zb, char* __restrict__ xb,
                          u32* __restrict__ bar) {
  int idx = blockIdx.x * 256 + threadIdx.x;       // 262144 threads
  f32x4 z = {0.f, 0.f, 0.f, 0.f};
  for (int i = idx; i < 393216; i += 262144) *(f32x4*)(zb + (size_t)i * 16) = z;
  for (int i = idx; i < 65536; i += 262144) {
    int row = i >> 6, j = i & 63;
    *(f32x4*)(xb + (size_t)row * (K1K * 2) + CODE * 2 + (size_t)j * 16) = z;
  }
  if (idx < 16) bar[idx] = 0u;
}

// idea = tanh(latent @ w_unpack + b); also xbuf[:,0:2048] = idea (att0 = 1)
__global__ void idea_kernel(const float* __restrict__ latent, const float* __restrict__ w,
                            const float* __restrict__ b,
                            __hip_bfloat16* __restrict__ idea_bf,
                            __hip_bfloat16* __restrict__ x_bf) {
  int idx = blockIdx.x * 256 + threadIdx.x;       // 2M = 1024*2048
  int bi = idx >> 11, j = idx & 2047;
  const float* lr = latent + bi * 128;
  float s = b[j];
#pragma unroll 8
  for (int k = 0; k < 128; ++k) s = fmaf(lr[k], w[(size_t)k * CODE + j], s);
  __hip_bfloat16 h = __float2bfloat16(tanhf(s));
  idea_bf[idx] = h;
  x_bf[(size_t)bi * K1K + j] = h;
}

// ---- manual grid barrier (all NBLK blocks co-resident by construction) -----
DEVI void gridbar(u32* bar, u32 target) {
  __syncthreads();
  __threadfence();   // release: make this block's writes agent-visible
  if (threadIdx.x == 0) {
    __hip_atomic_fetch_add(bar, 1u, __ATOMIC_RELEASE, __HIP_MEMORY_SCOPE_AGENT);
    while (__hip_atomic_load(bar, __ATOMIC_ACQUIRE, __HIP_MEMORY_SCOPE_AGENT) < target)
      __builtin_amdgcn_s_sleep(2);
  }
  __syncthreads();
  __threadfence();   // acquire: invalidate stale cached lines before reading
}

// ---- shared GEMM inner-loop fragments (identical to round-10 verified core) -
// BM=64, BN=64, BK=64; 256 threads = 4 waves (2x2), wave tile 32x32.
// Grid 512 = 2 blocks/CU (cross-block co-scheduling covers barrier stalls).
// LDS: A[64][128B] @0, B[64][128B] @8192 (involution: LDS[r*128+q] holds
// global (r, q ^ ((r&7)<<4))). 16 1KB chunks, 4/wave. 3 buffers, depth-2
// prefetch, counted s_waitcnt vmcnt(4) + raw s_barrier.

#define STAGE(KO, DST)                                                        \
  _Pragma("unroll") for (int j = 0; j < 4; ++j)                               \
      g2l16(gp[j] + (KO), (DST) + ldsc[j]);

#define COMPUTE(SB)                                                           \
  __builtin_amdgcn_s_setprio(1);                                              \
  _Pragma("unroll") for (int kk = 0; kk < 2; ++kk) {                          \
    bf16x8 av[2], bv[2];                                                      \
    _Pragma("unroll") for (int fm = 0; fm < 2; ++fm)                          \
        av[fm] = *(const bf16x8*)((SB) + aoff[fm][kk]);                       \
    _Pragma("unroll") for (int fn = 0; fn < 2; ++fn)                          \
        bv[fn] = *(const bf16x8*)((SB) + boff[fn][kk]);                       \
    _Pragma("unroll") for (int fm = 0; fm < 2; ++fm)                          \
      _Pragma("unroll") for (int fn = 0; fn < 2; ++fn)                        \
        acc[fm][fn] = __builtin_amdgcn_mfma_f32_16x16x32_bf16(                \
            av[fm], bv[fn], acc[fm][fn], 0, 0, 0);                            \
  }                                                                           \
  __builtin_amdgcn_s_setprio(0);

#define WAITB(N)                                                              \
  asm volatile("s_waitcnt vmcnt(" #N ")" ::: "memory");                       \
  __builtin_amdgcn_s_barrier();                                               \
  asm volatile("" ::: "memory");

#define GEMM_SETUP(AB, AKB, BB, BKB)                                          \
  const int lane = tid & 63, wv = tid >> 6;                                   \
  const int rl = lane >> 3;                                                   \
  const int cswz = ((lane & 7) * 16) ^ (rl << 4);                             \
  const char* gp[4]; int ldsc[4];                                             \
  _Pragma("unroll") for (int j = 0; j < 4; ++j) {                             \
    int c = wv * 4 + j;                                                       \
    int row = (c < 8) ? (m0 + c * 8 + rl) : (n0 + (c - 8) * 8 + rl);          \
    gp[j] = ((c < 8) ? (AB) : (BB)) +                                         \
            (size_t)row * ((c < 8) ? (AKB) : (BKB)) + cswz;                   \
    ldsc[j] = c * 1024;                                                       \
  }                                                                           \
  const int l16 = lane & 15, lg = lane >> 4;                                  \
  const int wr = wv & 1, wc = wv >> 1;                                        \
  const int xm = (l16 & 7) << 4;                                              \
  int aoff[2][2], boff[2][2];                                                 \
  _Pragma("unroll") for (int fm = 0; fm < 2; ++fm) {                          \
    int r = wr * 32 + fm * 16 + l16;                                          \
    _Pragma("unroll") for (int kk = 0; kk < 2; ++kk)                          \
      aoff[fm][kk] = r * 128 + ((kk * 64 + lg * 16) ^ xm);                    \
  }                                                                           \
  _Pragma("unroll") for (int fn = 0; fn < 2; ++fn) {                          \
    int r = wc * 32 + fn * 16 + l16;                                          \
    _Pragma("unroll") for (int kk = 0; kk < 2; ++kk)                          \
      boff[fn][kk] = 8192 + r * 128 + ((kk * 64 + lg * 16) ^ xm);             \
  }                                                                           \
  f32x4 z4 = {0.f, 0.f, 0.f, 0.f};                                            \
  f32x4 acc[2][2];                                                            \
  _Pragma("unroll") for (int a = 0; a < 2; ++a)                               \
    _Pragma("unroll") for (int b = 0; b < 2; ++b) acc[a][b] = z4;

#define GEMM_PIPELINE(NK)                                                     \
  STAGE(0, smem);                                                             \
  STAGE(128, smem + BUFSZ);                                                   \
  for (int kt = 0; kt < (NK) - 1; ++kt) {                                     \
    WAITB(4);                                                                 \
    if (kt + 2 < (NK)) {                                                      \
      char* nb = smem + ((kt + 2) % 3) * BUFSZ;                               \
      STAGE((size_t)(kt + 2) * 128, nb);                                      \
    }                                                                         \
    const char* sb = smem + (kt % 3) * BUFSZ;                                 \
    COMPUTE(sb);                                                              \
  }                                                                           \
  WAITB(0);                                                                   \
  COMPUTE(smem + (((NK) - 1) % 3) * BUFSZ);

// ---- phase bodies (inlined into the persistent kernel) ---------------------

DEVI void gemm_cell(char* smem, int tid, int m0, int n0,
                    const char* Ab, int akb, const char* Bb, int bkb, int nk,
                    const float* bias, float* c_state,
                    __hip_bfloat16* hd0, int ld0,
                    bool heads, const float* w_ang, const float* w_wid,
                    float* partial) {
  GEMM_SETUP(Ab, akb, Bb, bkb)
  GEMM_PIPELINE(nk)

  __syncthreads();
  float* gsm = (float*)smem;  // [64][68]
#pragma unroll
  for (int fm = 0; fm < 2; ++fm)
#pragma unroll
    for (int fn = 0; fn < 2; ++fn) {
      int col = wc * 32 + fn * 16 + l16;
#pragma unroll
      for (int j = 0; j < 4; ++j)
        gsm[(wr * 32 + fm * 16 + lg * 4 + j) * 68 + col] = acc[fm][fn][j];
    }
  __syncthreads();
#pragma unroll
  for (int i = 0; i < 4; ++i) {
    int p = tid + i * 256;            // 1024 = 64 rows x 16 units
    int unit = p & 15, row = p >> 4;
    f32x4 g = *(const f32x4*)(gsm + row * 68 + unit * 4);
    f32x4 bb = *(const f32x4*)(bias + n0 + unit * 4);
    float ig = sigf(g.x + bb.x);
    float fg = sigf(g.y + bb.y);
    float gg = tanhf(g.z + bb.z);
    float og = sigf(g.w + bb.w);
    int grow = m0 + row, gu = (n0 >> 2) + unit;
    float cold = c_state[grow * RNN + gu];
    float cn = fg * cold + ig * gg;
    c_state[grow * RNN + gu] = cn;
    float h = og * tanhf(cn);
    hd0[(size_t)grow * ld0 + gu] = __float2bfloat16(h);
    if (heads) {
      float pa = h * w_ang[gu], pw = h * w_wid[gu];
#pragma unroll
      for (int m = 1; m < 16; m <<= 1) {
        pa += __shfl_xor(pa, m);
        pw += __shfl_xor(pw, m);
      }
      if ((tid & 15) == 0) {
        float* pp = partial + ((size_t)(n0 >> 6) * 1024 + grow) * 2;
        pp[0] = pa; pp[1] = pw;
      }
    }
  }
}

DEVI void gemm_att(char* smem, int tid, int m0, int n0,
                   const char* Ab, int akb, const char* Bb, int bkb,
                   const float* bo, const __hip_bfloat16* idea_bf,
                   __hip_bfloat16* xbuf,
                   const float* partial, const float* b_ang, const float* b_wid,
                   float* out, int t) {
  GEMM_SETUP(Ab, akb, Bb, bkb)
  GEMM_PIPELINE(K3K / 64)

#pragma unroll
  for (int fn = 0; fn < 2; ++fn) {
    int col = n0 + wc * 32 + fn * 16 + l16;
    float bia = bo[col];
#pragma unroll
    for (int fm = 0; fm < 2; ++fm)
#pragma unroll
      for (int j = 0; j < 4; ++j) {
        int row = m0 + wr * 32 + fm * 16 + lg * 4 + j;
        float a = sigf(acc[fm][fn][j] + bia);
        float id = __bfloat162float(idea_bf[(size_t)row * CODE + col]);
        xbuf[(size_t)row * K1K + col] = __float2bfloat16(id * a);
      }
  }

  // heads finalize: 16 blocks (n0==0), 64 rows x 2 outputs each
  if (n0 == 0 && tid < 128) {
    int row = m0 + (tid >> 1), g = tid & 1;
    float s = g ? b_wid[0] : b_ang[0];
#pragma unroll
    for (int j = 0; j < 32; ++j) s += partial[((size_t)j * 1024 + row) * 2 + g];
    out[(size_t)row * (TSTEPS * 2) + t * 2 + g] = g ? sigf(s) : tanhf(s);
  }
}

// ---------------------------------------------------------------------------
// Persistent kernel (normal launch): all 128 steps; manual grid barrier at
// the 3 dependency points per step. Grid 512 x 256 = 2 blocks/CU, co-resident
// by construction (LDS 48KB -> 3/CU cap; __launch_bounds__(256,2) VGPR cap).
// ---------------------------------------------------------------------------
struct PParams {
  char* xbuf;
  const char* W1T; const char* W2T; const char* WoT;
  const float* b1p; const float* b2p; const float* bo;
  float* c1; float* c2;
  __hip_bfloat16* hb0; __hip_bfloat16* hb1;
  const __hip_bfloat16* idea;
  float* partial;
  const float* w_ang; const float* w_wid;
  const float* b_ang; const float* b_wid;
  float* out;
  u32* bar;
};

__global__ void __launch_bounds__(256, 2) persistent_kernel(PParams p) {
  __shared__ char smem[3 * BUFSZ];  // 48KB
  const int tid = threadIdx.x;
  const int l = blockIdx.x;              // 512 blocks, XCD-swizzled
  const int xcd = l & 7, bi = l >> 3;    // bi 0..63
  const int n0 = (xcd * 4 + (bi & 3)) * 64;
  const int m0 = (bi >> 2) * 64;
  const int j16 = n0 >> 6;               // 0..31
  u32 ep = 0;

  for (int t = 0; t < TSTEPS; ++t) {
    __hip_bfloat16* hc = (t & 1) ? p.hb1 : p.hb0;   // [h1(t) | h2(t-1)]
    __hip_bfloat16* hn = (t & 1) ? p.hb0 : p.hb1;   // next-step buffer

    // phase 1: gates1 = xbuf @ W1 ; cell -> c1, h1 -> hc[:,0:512]
    gemm_cell(smem, tid, m0, n0, p.xbuf, K1K * 2, p.W1T, K1K * 2, K1K / 64,
              p.b1p, p.c1, hc, 1024, false, nullptr, nullptr, nullptr);
    gridbar(p.bar, ++ep * NBLK);

    // phase 2: gates2 = hc @ W2 ; cell -> c2, h2 -> hn[:,512:1024]; head partials
    gemm_cell(smem, tid, m0, n0, (const char*)hc, K2K * 2, p.W2T, K2K * 2,
              K2K / 64, p.b2p, p.c2, hn + RNN, 1024, true, p.w_ang, p.w_wid,
              p.partial);
    gridbar(p.bar, ++ep * NBLK);

    // phase 3: h1 strip copy + att GEMM + heads finalize
    if (tid < 128) {
      int row = m0 + (tid >> 1), cb = (tid & 1) * 16;
      *(f32x4*)(p.xbuf + (size_t)row * (K1K * 2) + CODE * 2 + j16 * 32 + cb) =
          *(const f32x4*)((const char*)hc + (size_t)row * 2048 + j16 * 32 + cb);
    }
    gemm_att(smem, tid, m0, n0, (const char*)hn + 1024, 2048,
             p.WoT, K3K * 2, p.bo, p.idea, (__hip_bfloat16*)p.xbuf,
             p.partial, p.b_ang, p.b_wid, p.out, t);
    gridbar(p.bar, ++ep * NBLK);
  }
}

// ---------------------------------------------------------------------------
extern "C" void kernel_launch(void* const* d_in, const int* in_sizes, int n_in,
                              void* d_out, int out_size, void* d_ws, size_t ws_size,
                              hipStream_t stream) {
  const float* latent = (const float*)d_in[0];
  const float* w_unp  = (const float*)d_in[2];
  const float* b_unp  = (const float*)d_in[3];
  const float* w_ih1  = (const float*)d_in[4];
  const float* w_hh1  = (const float*)d_in[5];
  const float* b_ih1  = (const float*)d_in[6];
  const float* b_hh1  = (const float*)d_in[7];
  const float* w_ih2  = (const float*)d_in[8];
  const float* w_hh2  = (const float*)d_in[9];
  const float* b_ih2  = (const float*)d_in[10];
  const float* b_hh2  = (const float*)d_in[11];
  const float* w_att  = (const float*)d_in[12];
  const float* b_att  = (const float*)d_in[13];
  const float* w_wid  = (const float*)d_in[14];
  const float* b_wid  = (const float*)d_in[15];
  const float* w_ang  = (const float*)d_in[16];
  const float* b_ang  = (const float*)d_in[17];
  float* out = (float*)d_out;

  char* ws = (char*)d_ws;
  __hip_bfloat16* W1T  = (__hip_bfloat16*)(ws + 0);          // 2048 x 2560
  __hip_bfloat16* W2T  = (__hip_bfloat16*)(ws + 10485760);   // 2048 x 1024
  __hip_bfloat16* WoT  = (__hip_bfloat16*)(ws + 14680064);   // 2048 x 512
  float* b1p           = (float*)(ws + 16777216);            // 2048
  float* b2p           = (float*)(ws + 16785408);            // 2048
  float* bo            = (float*)(ws + 16793600);            // 2048
  __hip_bfloat16* idea = (__hip_bfloat16*)(ws + 16801792);   // 1024 x 2048
  __hip_bfloat16* xbuf = (__hip_bfloat16*)(ws + 20996096);   // 1024 x 2560 [idea*att | h1]
  __hip_bfloat16* hb0  = (__hip_bfloat16*)(ws + 26238976);   // 1024 x 1024 [h1|h2]
  float* c1            = (float*)(ws + 28336128);            // 1024 x 512
  float* c2            = (float*)(ws + 30433280);            // 1024 x 512
  __hip_bfloat16* hb1  = (__hip_bfloat16*)(ws + 32530432);   // 1024 x 1024
  float* partial       = (float*)(ws + 34627584);            // 32 x 1024 x 2
  u32* bar             = (u32*)(ws + 34889728);              // grid barrier counter

  conv_w1<<<2048, 256, 0, stream>>>(w_ih1, w_hh1, W1T);
  conv_w2<<<2048, 256, 0, stream>>>(w_ih2, w_hh2, W2T);
  conv_wo<<<2048, 256, 0, stream>>>(w_att, WoT);
  conv_b<<<8, 256, 0, stream>>>(b_ih1, b_hh1, b_ih2, b_hh2, b_att, b1p, b2p, bo);
  init_zero<<<1024, 256, 0, stream>>>(ws + 26238976, (char*)xbuf, bar);
  idea_kernel<<<8192, 256, 0, stream>>>(latent, w_unp, b_unp, idea, xbuf);

  PParams prm;
  prm.xbuf = (char*)xbuf;
  prm.W1T = (const char*)W1T; prm.W2T = (const char*)W2T; prm.WoT = (const char*)WoT;
  prm.b1p = b1p; prm.b2p = b2p; prm.bo = bo;
  prm.c1 = c1; prm.c2 = c2;
  prm.hb0 = hb0; prm.hb1 = hb1;
  prm.idea = idea;
  prm.partial = partial;
  prm.w_ang = w_ang; prm.w_wid = w_wid;
  prm.b_ang = b_ang; prm.b_wid = b_wid;
  prm.out = out;
  prm.bar = bar;
  persistent_kernel<<<NBLK, 256, 0, stream>>>(prm);
}